// Round 1
// 1098.782 us; speedup vs baseline: 1.2403x; 1.2403x over previous
//
#include <hip/hip_runtime.h>
#include <hip/hip_bf16.h>
#include <math.h>

// ConvBlockFD R3: aux-kernel pass.
// - gap_t_part: 1024-thread blocks, short8 vector loads, LDS reduce
//   (was: 256 blocks x 1024 serial scalar bf16 loads -> latency-bound).
// - fd_synth_t: ci-fastest thread mapping -> coalesced weight reads
//   (was: co-fastest -> 6KB-stride 24B chunks).
// Conv kernels unchanged (conv2 at m97-structure ceiling, 35% MfmaUtil).

#define K_NUM 4
typedef __attribute__((ext_vector_type(8))) short short8;   // 8 bf16 = 4 VGPR
typedef __attribute__((ext_vector_type(4))) float f32x4;    // MFMA C/D frag

__device__ inline float bf2f(short s) {
  unsigned u = ((unsigned)(unsigned short)s) << 16;
  return __uint_as_float(u);
}
__device__ inline short f2bf(float f) {
  __hip_bfloat16 h = __float2bfloat16(f);
  return (short)*reinterpret_cast<unsigned short*>(&h);
}

// ---------------- GAP over fp32 NCHW (layer 1) ----------------
__global__ void fd_gap_kernel(const float* __restrict__ x, float* __restrict__ out, int HW) {
  const float4* p = (const float4*)(x + (size_t)blockIdx.x * HW);
  int n4 = HW >> 2;
  float s = 0.f;
  for (int i = threadIdx.x; i < n4; i += blockDim.x) {
    float4 v = p[i];
    s += v.x + v.y + v.z + v.w;
  }
  for (int off = 32; off > 0; off >>= 1) s += __shfl_down(s, off, 64);
  __shared__ float wsum[4];
  int lane = threadIdx.x & 63, w = threadIdx.x >> 6;
  if (lane == 0) wsum[w] = s;
  __syncthreads();
  if (threadIdx.x == 0) {
    float t = 0.f;
    int nw = blockDim.x >> 6;
    for (int i = 0; i < nw; ++i) t += wsum[i];
    out[blockIdx.x] = t / (float)HW;
  }
}

// ---------------- GAP over bf16 channels-last (layer 2) ----------------
// Block: 1024 threads. tg = co-octet (32 groups of 8 co), pg = px slot (32).
// Each thread: 32 short8 loads (16B, coalesced), 8 fp32 accumulators.
__global__ __launch_bounds__(1024) void gap_t_part_kernel(
    const short* __restrict__ y, float* __restrict__ part) {
  const int HW = 16384, CO = 256;
  int b = blockIdx.y, ch = blockIdx.x;             // 16 chunks x 1024 px
  int t = threadIdx.x;
  int tg = t & 31, pg = t >> 5;
  const short* base = y + ((size_t)b * HW + (size_t)ch * 1024) * CO + tg * 8;
  float s[8];
#pragma unroll
  for (int j = 0; j < 8; ++j) s[j] = 0.f;
  for (int px = pg; px < 1024; px += 32) {
    short8 v = *(const short8*)(base + (size_t)px * CO);
#pragma unroll
    for (int j = 0; j < 8; ++j) s[j] += bf2f(v[j]);
  }
  __shared__ float red[32][32][8];  // 32 KB
#pragma unroll
  for (int j = 0; j < 8; ++j) red[pg][tg][j] = s[j];
  __syncthreads();
  if (t < 256) {
    float tot = 0.f;
    const float* r = (const float*)red;
#pragma unroll
    for (int p = 0; p < 32; ++p) tot += r[p * 256 + t];
    part[((size_t)b * 16 + ch) * 256 + t] = tot;
  }
}
__global__ void gap_t_reduce_kernel(const float* __restrict__ part, float* __restrict__ gap) {
  int b = blockIdx.x, co = threadIdx.x;
  float s = 0.f;
  for (int c = 0; c < 16; ++c) s += part[(b * 16 + c) * 256 + co];
  gap[b * 256 + co] = s * (1.f / 16384.f);
}

// ---------------- attention MLP + softmax ----------------
__global__ void fd_attn_kernel(const float* __restrict__ gap, int C, int Hd,
                               const float* __restrict__ w1, const float* __restrict__ b1,
                               const float* __restrict__ w2, const float* __restrict__ b2,
                               float* __restrict__ attn) {
  int b = blockIdx.x, j = threadIdx.x;
  __shared__ float h[64];
  __shared__ float z[K_NUM];
  if (j < Hd) {
    float s = b1[j];
    const float* g = gap + (size_t)b * C;
    for (int c = 0; c < C; ++c) s = fmaf(g[c], w1[c * Hd + j], s);
    h[j] = fmaxf(s, 0.f);
  }
  __syncthreads();
  if (j < K_NUM) {
    float s = b2[j];
    for (int c = 0; c < Hd; ++c) s = fmaf(h[c], w2[c * K_NUM + j], s);
    z[j] = s;
  }
  __syncthreads();
  if (j == 0) {
    float m = z[0];
    for (int k = 1; k < K_NUM; ++k) m = fmaxf(m, z[k]);
    float e[K_NUM], sum = 0.f;
    for (int k = 0; k < K_NUM; ++k) { e[k] = expf(z[k] - m); sum += e[k]; }
    for (int k = 0; k < K_NUM; ++k) attn[b * K_NUM + k] = e[k] / sum;
  }
}

// ---------------- synthesis: irfft2 + attention mix -> wd_t[b][9][ci/8][co][8] bf16 ----
// ci-fastest mapping: consecutive lanes read consecutive 24B coeff chunks (coalesced).
__global__ void fd_synth_t_kernel(const float* __restrict__ wfr, const float* __restrict__ wfi,
                                  const float* __restrict__ attn, short* __restrict__ wdt,
                                  int B, int CO, int CI) {
  size_t gid = (size_t)blockIdx.x * blockDim.x + threadIdx.x;
  size_t total = (size_t)B * CI * CO;
  if (gid >= total) return;
  int ci = (int)(gid % CI);
  size_t t = gid / CI;
  int co = (int)(t % CO);
  int b = (int)(t / CO);

  float a[K_NUM];
  for (int k = 0; k < K_NUM; ++k) a[k] = attn[b * K_NUM + k];

  float Fr[3][2], Fi[3][2];
  for (int u = 0; u < 3; ++u) for (int v = 0; v < 2; ++v) { Fr[u][v] = 0.f; Fi[u][v] = 0.f; }
  for (int k = 0; k < K_NUM; ++k) {
    size_t base = ((((size_t)k * CO + co) * CI + ci) * 3) * 2;
    const float* pr = wfr + base;
    const float* pi = wfi + base;
    float ak = a[k];
    for (int u = 0; u < 3; ++u)
      for (int v = 0; v < 2; ++v) {
        Fr[u][v] = fmaf(ak, pr[u * 2 + v], Fr[u][v]);
        Fi[u][v] = fmaf(ak, pi[u * 2 + v], Fi[u][v]);
      }
  }

  const float CS[3] = {1.f, -0.5f, -0.5f};
  const float SN[3] = {0.f, 0.8660254037844386f, -0.8660254037844386f};
  float outv[9];
  for (int ai = 0; ai < 3; ++ai) {
    float Gr[2], Gi[2];
    for (int v = 0; v < 2; ++v) {
      float gr = 0.f, gi = 0.f;
      for (int u = 0; u < 3; ++u) {
        int idx = (u * ai) % 3;
        gr += Fr[u][v] * CS[idx] - Fi[u][v] * SN[idx];
        gi += Fr[u][v] * SN[idx] + Fi[u][v] * CS[idx];
      }
      Gr[v] = gr * (1.f / 3.f);
      Gi[v] = gi * (1.f / 3.f);
    }
    for (int bi = 0; bi < 3; ++bi)
      outv[ai * 3 + bi] = (Gr[0] + 2.f * (Gr[1] * CS[bi] - Gi[1] * SN[bi])) * (1.f / 3.f);
  }
  int ci8 = ci >> 3, cil = ci & 7;
  for (int s = 0; s < 9; ++s)
    wdt[((((size_t)b * 9 + s) * (CI / 8) + ci8) * CO + co) * 8 + cil] = f2bf(outv[s]);
}

// ---------------- transpose fp32 NCHW -> bf16 channels-last ----------------
__global__ __launch_bounds__(256) void transpose_bf16_kernel(
    const float* __restrict__ in, short* __restrict__ out, int C) {
  const int HW = 16384;
  __shared__ short t[64 * 40];
  int tid = threadIdx.x;
  int px0 = blockIdx.x * 64, c0 = blockIdx.y * 32, b = blockIdx.z;
  int px = tid & 63, cb = tid >> 6;
#pragma unroll
  for (int i = 0; i < 8; ++i) {
    int c = i * 4 + cb;
    float v = in[((size_t)b * C + c0 + c) * HW + px0 + px];
    t[px * 40 + c] = f2bf(v);
  }
  __syncthreads();
  int px2 = tid >> 2, g = tid & 3;
  short8 v = *(const short8*)(t + px2 * 40 + g * 8);
  *(short8*)(out + ((size_t)b * HW + px0 + px2) * C + c0 + g * 8) = v;
}

// ---------------- MFMA conv: 9 shift-GEMMs, 16x16x32 bf16 ----------------
// Block: 64 co x 256 px (16x16 tile); wave: 64 co x 64 px (4x4 frags).
// MODE 0 (conv1): D=[px][co], writes bf16 channels-last. MODE 1 (conv2): D=[co][px], fp32 NCHW.
template <int CI, int MODE>
__global__ __launch_bounds__(256) void conv_mfma_kernel(
    const short* __restrict__ xin,   // [B][HW][CI] bf16
    const short* __restrict__ wdt,   // [B][9][CI/8][256][8] bf16
    const float* __restrict__ bias,  // [256]
    short* __restrict__ yout_t,      // MODE0 out
    float* __restrict__ yout_f) {    // MODE1 out
  const int H = 128, W = 128, HW = H * W, CO = 256;
  const int NKC = CI / 32;
  __shared__ short xs[18 * 18 * 40];  // [row18][col18][ci 32 pad 40] bf16

  const int tid = threadIdx.x;
  const int w = tid >> 6;
  const int lane = tid & 63;
  const int l15 = lane & 15, l4 = lane >> 4;
  const int tx0 = (blockIdx.x & 7) * 16, ty0 = (blockIdx.x >> 3) * 16;
  const int co0 = blockIdx.y * 64;
  const int b = blockIdx.z;

  f32x4 acc[4][4];
#pragma unroll
  for (int i = 0; i < 4; ++i)
#pragma unroll
    for (int j = 0; j < 4; ++j)
      acc[i][j] = (f32x4){0.f, 0.f, 0.f, 0.f};

  for (int kc = 0; kc < NKC; ++kc) {
    __syncthreads();
    // stage x tile: 18x18 px halo x 32 ci -> 1296 16B chunks
#pragma unroll
    for (int i = 0; i < 6; ++i) {
      int idx = i * 256 + tid;
      if (idx < 1296) {
        int pxi = idx >> 2, g = idx & 3;
        int r = pxi / 18, c = pxi - r * 18;
        int gy = ty0 + r - 1, gx = tx0 + c - 1;
        short8 v = {0, 0, 0, 0, 0, 0, 0, 0};
        if ((unsigned)gy < (unsigned)H && (unsigned)gx < (unsigned)W)
          v = *(const short8*)(xin + ((size_t)b * HW + gy * W + gx) * CI + kc * 32 + g * 8);
        *(short8*)(xs + pxi * 40 + g * 8) = v;
      }
    }
    __syncthreads();

#pragma unroll
    for (int dc = 0; dc < 3; ++dc) {
      // x frags: 6 distinct rows cover all (nf, dr) pairs
      short8 xf[6];
#pragma unroll
      for (int rr = 0; rr < 6; ++rr)
        xf[rr] = *(const short8*)(xs + ((4 * w + rr) * 18 + l15 + dc) * 40 + l4 * 8);
      // w frags for all 3 dr of this dc (from L2, lane-contiguous 16B)
      short8 wf[3][4];
#pragma unroll
      for (int dr = 0; dr < 3; ++dr) {
        const short* wp = wdt + ((((size_t)b * 9 + dr * 3 + dc) * (CI / 8) + kc * 4 + l4) * CO + co0 + l15) * 8;
#pragma unroll
        for (int cf = 0; cf < 4; ++cf)
          wf[dr][cf] = *(const short8*)(wp + cf * 128);
      }
#pragma unroll
      for (int dr = 0; dr < 3; ++dr)
#pragma unroll
        for (int nf = 0; nf < 4; ++nf)
#pragma unroll
          for (int cf = 0; cf < 4; ++cf) {
            if (MODE == 0)
              acc[nf][cf] = __builtin_amdgcn_mfma_f32_16x16x32_bf16(
                  xf[nf + dr], wf[dr][cf], acc[nf][cf], 0, 0, 0);
            else
              acc[nf][cf] = __builtin_amdgcn_mfma_f32_16x16x32_bf16(
                  wf[dr][cf], xf[nf + dr], acc[nf][cf], 0, 0, 0);
          }
    }
  }

  if (MODE == 0) {
    // D[m=px-col][n=co]: lane holds col = l4*4+r, co = l15; store bf16 channels-last
#pragma unroll
    for (int cf = 0; cf < 4; ++cf) {
      float bs = bias[co0 + cf * 16 + l15];
#pragma unroll
      for (int nf = 0; nf < 4; ++nf) {
        int row = ty0 + 4 * w + nf;
#pragma unroll
        for (int r = 0; r < 4; ++r) {
          int col = tx0 + l4 * 4 + r;
          float v = fmaxf(acc[nf][cf][r] + bs, 0.f);
          yout_t[((size_t)b * HW + (size_t)row * W + col) * CO + co0 + cf * 16 + l15] = f2bf(v);
        }
      }
    }
  } else {
    // D[m=co][n=px-col]: lane holds co = l4*4+r, col = l15; store fp32 NCHW
#pragma unroll
    for (int cf = 0; cf < 4; ++cf) {
#pragma unroll
      for (int r = 0; r < 4; ++r) {
        int co = co0 + cf * 16 + l4 * 4 + r;
        float bs = bias[co];
#pragma unroll
        for (int nf = 0; nf < 4; ++nf) {
          int row = ty0 + 4 * w + nf;
          int col = tx0 + l15;
          yout_f[((size_t)b * CO + co) * HW + (size_t)row * W + col] =
              fmaxf(acc[nf][cf][r] + bs, 0.f);
        }
      }
    }
  }
}

extern "C" void kernel_launch(void* const* d_in, const int* in_sizes, int n_in,
                              void* d_out, int out_size, void* d_ws, size_t ws_size,
                              hipStream_t stream) {
  const int B = 16, CIN = 128, COUT = 256, H = 128, W = 128, HW = H * W;

  const float* x    = (const float*)d_in[0];
  const float* w1fr = (const float*)d_in[1];
  const float* w1fi = (const float*)d_in[2];
  const float* b1   = (const float*)d_in[3];
  const float* a1w1 = (const float*)d_in[4];
  const float* a1b1 = (const float*)d_in[5];
  const float* a1w2 = (const float*)d_in[6];
  const float* a1b2 = (const float*)d_in[7];
  const float* w2fr = (const float*)d_in[8];
  const float* w2fi = (const float*)d_in[9];
  const float* b2   = (const float*)d_in[10];
  const float* a2w1 = (const float*)d_in[11];
  const float* a2b1 = (const float*)d_in[12];
  const float* a2w2 = (const float*)d_in[13];
  const float* a2b2 = (const float*)d_in[14];
  float* outf = (float*)d_out;

  // xt (67MB bf16) parked in d_out: read only by conv1; conv2 overwrites d_out last.
  short* xt = (short*)d_out;

  char* wsb = (char*)d_ws;
  short* y1t  = (short*)wsb;                                   // 134,217,728 B
  short* wdt  = (short*)(wsb + 134217728);                     //  18,874,368 B
  float* gprt = (float*)(wsb + 134217728 + 18874368);          //     262,144 B
  float* gap  = (float*)(wsb + 134217728 + 18874368 + 262144); //      16,384 B
  float* attn = (float*)(wsb + 134217728 + 18874368 + 262144 + 16384); // 256 B

  // ---- layer 1 ----
  transpose_bf16_kernel<<<dim3(HW / 64, CIN / 32, B), 256, 0, stream>>>(x, xt, CIN);
  fd_gap_kernel<<<B * CIN, 256, 0, stream>>>(x, gap, HW);
  fd_attn_kernel<<<B, 64, 0, stream>>>(gap, CIN, CIN / 4, a1w1, a1b1, a1w2, a1b2, attn);
  fd_synth_t_kernel<<<(B * CIN * COUT) / 256, 256, 0, stream>>>(w1fr, w1fi, attn, wdt, B, COUT, CIN);
  conv_mfma_kernel<128, 0><<<dim3(64, 4, 16), 256, 0, stream>>>(xt, wdt, b1, y1t, nullptr);

  // ---- layer 2 ----
  gap_t_part_kernel<<<dim3(16, B), 1024, 0, stream>>>(y1t, gprt);
  gap_t_reduce_kernel<<<B, 256, 0, stream>>>(gprt, gap);
  fd_attn_kernel<<<B, 64, 0, stream>>>(gap, COUT, COUT / 4, a2w1, a2b1, a2w2, a2b2, attn);
  fd_synth_t_kernel<<<(B * COUT * COUT) / 256, 256, 0, stream>>>(w2fr, w2fi, attn, wdt, B, COUT, COUT);
  conv_mfma_kernel<256, 1><<<dim3(64, 4, 16), 256, 0, stream>>>(y1t, wdt, b2, nullptr, outf);
}